// Round 5
// baseline (254.946 us; speedup 1.0000x reference)
//
#include <hip/hip_runtime.h>

#define TOKS   32768
#define NEXP   64
#define DDIM   1024
#define SEQ    8192
#define NBATCH 4
#define TPB    64      // tokens per block
#define STR    68      // epilogue row stride (floats)
#define CSTR   21      // candidate row stride
#define BK     128     // K-chunk
#define NCHK   (DDIM / BK)          // 8

typedef __attribute__((ext_vector_type(8)))  short short8v;  // 8 bf16 (4 VGPR) MFMA operand
typedef __attribute__((ext_vector_type(16))) float f32x16;   // 32x32 accumulator

// exact RNE float->bf16 (branchless), and exact bf16->float
__device__ __forceinline__ unsigned f2bf(float x) {
  unsigned u = __float_as_uint(x);
  return (u + 0x7fffu + ((u >> 16) & 1u)) >> 16;
}
__device__ __forceinline__ float bf2f(unsigned h) { return __uint_as_float(h << 16); }

// ---------------- W split setup: fp32 W -> fragment-ordered bf16 hi/lo ----------------
// W3[g][e] is a 64B record (g = 16-k group 0..63, e = expert 0..63):
//   [ 0:16) hi bf16 of W[e][g*16 + 0.. 8)
//   [16:32) hi bf16 of W[e][g*16 + 8..16)
//   [32:48) lo bf16 (residual) of k g*16+0..8
//   [48:64) lo bf16 of k g*16+8..16
// A wave's B-frag load (32 consecutive e, kh in {0,1}) is a dense 2KB region -> L2-friendly.
__global__ void moe_wsplit(const float* __restrict__ W, ushort* __restrict__ W3) {
  const int sid = blockIdx.x * 256 + threadIdx.x;   // 0..16383 16B-slots
  const int p  = sid & 3;
  const int e  = (sid >> 2) & 63;
  const int g  = sid >> 8;
  const int kh = p & 1;
  const int k0 = g * 16 + kh * 8;
  const float* src = W + (size_t)e * DDIM + k0;
  float f[8];
  *(float4*)&f[0] = *(const float4*)src;
  *(float4*)&f[4] = *(const float4*)(src + 4);
  ushort o[8];
  if (p < 2) {
#pragma unroll
    for (int j = 0; j < 8; ++j) o[j] = (ushort)f2bf(f[j]);
  } else {
#pragma unroll
    for (int j = 0; j < 8; ++j) {
      unsigned hb = f2bf(f[j]);
      o[j] = (ushort)f2bf(f[j] - bf2f(hb));
    }
  }
  *(short8v*)(W3 + (size_t)sid * 8) = *(const short8v*)o;
}

// ---------------- main kernel: X reg->LDS (full-iter slack), W from L2, 32x32x16 bf16x2 ----------------
__global__ __launch_bounds__(256, 3) void moe_gate_main(
    const float* __restrict__ X, const ushort* __restrict__ W3,
    float* __restrict__ out, float* __restrict__ gsum, float* __restrict__ gce,
    int* __restrict__ flag_cnt, int* __restrict__ flag_tok)
{
  // GEMM phase: X hi tile [64][128]bf16 @0 (16K), X lo tile @16384 (16K).
  // Epilogue aliases the same pool with the proven round-3 layout (47104 B).
  __shared__ __align__(16) char smem[47104];

  float* xs   = (float*)smem;            // scoresT [64][STR]
  float* wsm  = (float*)(smem + 17408);  // logits  [64][STR]
  float* red  = (float*)(smem + 34816);  // [256]
  float* gmx  = (float*)(smem + 35840);  // [64]
  float* cval = (float*)(smem + 36096);  // [64*CSTR]
  int*   cidx = (int*)  (smem + 41472);  // [64*CSTR]
  int*   hist = (int*)  (smem + 46848);  // [64]

  const int tid = threadIdx.x;
  const int tok_base = blockIdx.x * TPB;
  const int bb = blockIdx.x >> 7;        // 128 blocks per batch

  const int l = tid & 63, q = tid >> 6;
  const int wm = q >> 1, wn = q & 1;     // token half / expert half
  const int rr = l & 31;                 // A row (token) == B col (expert)
  const int kh = l >> 5;                 // k half within 16-step

  // ---- X staging map: 8 coalesced 1KB loads/wave, swizzled 8B ds_writes ----
  const int xr0 = tid >> 5;              // base row 0..7 (row = xr0 + 8i)
  const int xc  = tid & 31;              // 16B col within 512B f32 row
  const float* Xbase = X + (size_t)tok_base * DDIM;
  int wb[8];                             // swizzled LDS byte offsets (iteration-invariant)
#pragma unroll
  for (int i = 0; i < 8; ++i) {
    const int r = xr0 + 8 * i;
    wb[i] = r * 256 + ((((xc >> 1) ^ (r & 15)) << 4)) + ((xc & 1) * 8);
  }

  // ---- compute-phase bases ----
  const int abase = (wm * 32 + rr) * 256;      // A-tile byte row
  const int amask = (wm * 32 + rr) & 15;       // slot swizzle
  const ushort* Wb = W3 + (size_t)(wn * 32 + rr) * 32 + kh * 8;  // + g*2048 per group

  f32x16 accA = (f32x16)0.0f, accB = (f32x16)0.0f;

  float4 px[8];
  unsigned sh[16], sl[16];

#define LOADPX(kc) do { \
    const float* xsrc = Xbase + (kc) * BK; \
    _Pragma("unroll") \
    for (int i = 0; i < 8; ++i) \
      px[i] = *(const float4*)(xsrc + (size_t)(xr0 + 8 * i) * DDIM + xc * 4); \
  } while (0)

#define CONV() do { \
    _Pragma("unroll") \
    for (int i = 0; i < 8; ++i) { \
      unsigned h0 = f2bf(px[i].x), h1 = f2bf(px[i].y); \
      unsigned h2 = f2bf(px[i].z), h3 = f2bf(px[i].w); \
      sh[2 * i]     = h0 | (h1 << 16); \
      sh[2 * i + 1] = h2 | (h3 << 16); \
      sl[2 * i]     = f2bf(px[i].x - bf2f(h0)) | (f2bf(px[i].y - bf2f(h1)) << 16); \
      sl[2 * i + 1] = f2bf(px[i].z - bf2f(h2)) | (f2bf(px[i].w - bf2f(h3)) << 16); \
    } } while (0)

#define WRITE() do { \
    _Pragma("unroll") \
    for (int i = 0; i < 8; ++i) { \
      *(uint2*)(smem + wb[i])         = make_uint2(sh[2 * i], sh[2 * i + 1]); \
      *(uint2*)(smem + 16384 + wb[i]) = make_uint2(sl[2 * i], sl[2 * i + 1]); \
    } } while (0)

#define COMPUTE(kc) do { \
    _Pragma("unroll") \
    for (int s = 0; s < 8; ++s) { \
      const int g = (kc) * 8 + s; \
      const ushort* wp = Wb + (size_t)g * 2048; \
      short8v bh = *(const short8v*)wp; \
      short8v bl = *(const short8v*)(wp + 16); \
      const int aoff = abase + (((2 * s + kh) ^ amask) << 4); \
      short8v ah = *(const short8v*)(smem + aoff); \
      short8v al = *(const short8v*)(smem + 16384 + aoff); \
      accA = __builtin_amdgcn_mfma_f32_32x32x16_bf16(ah, bh, accA, 0, 0, 0); \
      accB = __builtin_amdgcn_mfma_f32_32x32x16_bf16(al, bh, accB, 0, 0, 0); \
      accA = __builtin_amdgcn_mfma_f32_32x32x16_bf16(ah, bl, accA, 0, 0, 0); \
    } } while (0)

  // ---- prologue: fill chunk 0 ----
  LOADPX(0);
  CONV();
  WRITE();
  __syncthreads();           // chunk 0 visible to all waves

#pragma unroll 1
  for (int kc = 0; kc < NCHK; ++kc) {
    if (kc + 1 < NCHK) LOADPX(kc + 1);   // issue early: latency hides under COMPUTE
    COMPUTE(kc);                          // LDS frags + L2-resident W3 frags + MFMA
    if (kc + 1 < NCHK) CONV();            // consumes px (loads land here, ~2k cyc slack)
    __syncthreads();                      // all reads of the X tile done
    if (kc + 1 < NCHK) {
      WRITE();                            // refill tile with chunk kc+1
      __syncthreads();
    }
  }

  // ---- C write: 32x32 C/D layout col=lane&31, row=(r&3)+8*(r>>2)+4*(lane>>5) ----
  {
    const int ccol = wn * 32 + rr;
#pragma unroll
    for (int r = 0; r < 16; ++r) {
      const int trow = wm * 32 + (r & 3) + 8 * (r >> 2) + 4 * kh;
      wsm[trow * STR + ccol] = accA[r] + accB[r];
    }
  }
  if (tid < 64) hist[tid] = 0;
  __syncthreads();

#undef LOADPX
#undef CONV
#undef WRITE
#undef COMPUTE

  // ---- epilogue (round-3 layout, unchanged) ----
  float* logits  = wsm;   // [t][STR]
  float* scoresT = xs;    // [e][STR]
  const int t = l;

  float m = -__builtin_huge_valf();
#pragma unroll
  for (int e = 0; e < 16; ++e) m = fmaxf(m, logits[t * STR + q * 16 + e]);
  red[q * 64 + t] = m;
  __syncthreads();
  float gm = fmaxf(fmaxf(red[t], red[64 + t]), fmaxf(red[128 + t], red[192 + t]));
  if (q == 0) gmx[t] = gm;
  float z = 0.0f;
#pragma unroll
  for (int e = 0; e < 16; ++e) {
    float ev = expf(logits[t * STR + q * 16 + e] - gm);
    scoresT[(q * 16 + e) * STR + t] = ev;
    z += ev;
  }
  __syncthreads();
  red[q * 64 + t] = z;
  __syncthreads();
  float Z = red[t] + red[64 + t] + red[128 + t] + red[192 + t];
  float invZ = 1.0f / Z;
#pragma unroll
  for (int e = 0; e < 16; ++e) scoresT[(q * 16 + e) * STR + t] *= invZ;
  __syncthreads();

  // aux partials: sum scores over this block's tokens, per expert
  {
    const int e = l, g = q;
    float s = 0.0f;
#pragma unroll
    for (int tt = 0; tt < 16; ++tt) s += scoresT[e * STR + g * 16 + tt];
    red[g * 64 + e] = s;
  }
  __syncthreads();
  if (tid < 64) {
    float tot = red[tid] + red[64 + tid] + red[128 + tid] + red[192 + tid];
    atomicAdd(&gsum[bb * 64 + tid], tot);
  }

  // top-9 phase 1: per half (32 experts), strict > + ascending scan == jax tie-break
  if (tid < 128) {
    const int h = tid >> 6;
    const int eb = h * 32;
#pragma unroll 1
    for (int k = 0; k < 9; ++k) {
      float mv = -1.0f; int mi = eb;
#pragma unroll 4
      for (int e = 0; e < 32; ++e) {
        float v = scoresT[(eb + e) * STR + t];
        if (v > mv) { mv = v; mi = eb + e; }
      }
      cval[t * CSTR + h * 9 + k] = mv;
      cidx[t * CSTR + h * 9 + k] = mi;
      scoresT[mi * STR + t] = -1.0f;
    }
  }
  __syncthreads();

  // merge 18 -> top-9; flag near-ties for f64 refinement
  if (tid < 64) {
    float wv[9]; int wi[8];
#pragma unroll 1
    for (int k = 0; k < 9; ++k) {
      float mv = -1.0f; int mj = 0;
#pragma unroll 3
      for (int j = 0; j < 18; ++j) {
        float v = cval[t * CSTR + j];
        if (v > mv) { mv = v; mj = j; }
      }
      wv[k] = mv;
      if (k < 8) {
        wi[k] = cidx[t * CSTR + mj];
        atomicAdd(&hist[wi[k]], 1);
      }
      cval[t * CSTR + mj] = -1.0f;
    }
    bool flag = false;
#pragma unroll
    for (int k = 0; k < 8; ++k)
      if (wv[k + 1] >= wv[k] * (1.0f - 2.0e-5f)) flag = true;
    if (flag) {
      int p = atomicAdd(flag_cnt, 1);
      flag_tok[p] = tok_base + t;
    }
    // weights from f64 exp of logits (Z cancels in renorm; eps 1e-20 negligible)
    double ed[8]; double den = 0.0;
#pragma unroll
    for (int k = 0; k < 8; ++k) {
      ed[k] = exp((double)logits[t * STR + wi[k]] - (double)gmx[t]);
      den += ed[k];
    }
    const size_t tg = (size_t)(tok_base + t);
    *(float4*)(out + tg * 8) =
        make_float4((float)wi[0], (float)wi[1], (float)wi[2], (float)wi[3]);
    *(float4*)(out + tg * 8 + 4) =
        make_float4((float)wi[4], (float)wi[5], (float)wi[6], (float)wi[7]);
    *(float4*)(out + (size_t)TOKS * 8 + tg * 8) =
        make_float4((float)(ed[0] / den), (float)(ed[1] / den),
                    (float)(ed[2] / den), (float)(ed[3] / den));
    *(float4*)(out + (size_t)TOKS * 8 + tg * 8 + 4) =
        make_float4((float)(ed[4] / den), (float)(ed[5] / den),
                    (float)(ed[6] / den), (float)(ed[7] / den));
  }
  __syncthreads();
  if (tid < 64) atomicAdd(&gce[bb * 64 + tid], (float)hist[tid]);
}

// ---------------- f64 refinement for flagged (near-tie) tokens ----------------
__global__ __launch_bounds__(256) void moe_refine(
    const float* __restrict__ X, const float* __restrict__ W,
    float* __restrict__ out, float* __restrict__ gce,
    const int* __restrict__ flag_cnt, const int* __restrict__ flag_tok)
{
  __shared__ __align__(16) float xrow[DDIM];
  __shared__ double part[4][NEXP];
  const int tid = threadIdx.x;
  const int n = *flag_cnt;
  const int e = tid & 63;
  const int c = tid >> 6;          // K-chunk of 256
#pragma unroll 1
  for (int it = blockIdx.x; it < n; it += 256) {
    const int tok = flag_tok[it];
    __syncthreads();
    *(float4*)&xrow[tid * 4] = *(const float4*)&X[(size_t)tok * DDIM + tid * 4];
    __syncthreads();
    const float* wr = W + (size_t)e * DDIM + c * 256;
    const float* xr = xrow + c * 256;
    double s0 = 0.0, s1 = 0.0, s2 = 0.0, s3 = 0.0;
#pragma unroll 4
    for (int j = 0; j < 256; j += 4) {
      s0 += (double)xr[j]     * (double)wr[j];
      s1 += (double)xr[j + 1] * (double)wr[j + 1];
      s2 += (double)xr[j + 2] * (double)wr[j + 2];
      s3 += (double)xr[j + 3] * (double)wr[j + 3];
    }
    part[c][e] = (s0 + s1) + (s2 + s3);
    __syncthreads();
    if (tid < 64) {
      double cur = (part[0][e] + part[1][e]) + (part[2][e] + part[3][e]);
      int wi[8]; double wl[8];
#pragma unroll 1
      for (int k = 0; k < 8; ++k) {
        double mv = cur; int mi = e;
#pragma unroll
        for (int off = 1; off < 64; off <<= 1) {
          double ov = __shfl_xor(mv, off);
          int    oi = __shfl_xor(mi, off);
          if (ov > mv || (ov == mv && oi < mi)) { mv = ov; mi = oi; }
        }
        wi[k] = mi; wl[k] = mv;
        if (e == mi) cur = -1.0e300;   // knock out winner in its owner lane
      }
      if (e == 0) {
        int olde[8];
#pragma unroll
        for (int k = 0; k < 8; ++k) olde[k] = (int)out[(size_t)tok * 8 + k];
        double ex[8]; double den = 0.0;
#pragma unroll
        for (int k = 0; k < 8; ++k) { ex[k] = exp(wl[k] - wl[0]); den += ex[k]; }
#pragma unroll
        for (int k = 0; k < 8; ++k) {
          out[(size_t)tok * 8 + k] = (float)wi[k];
          out[(size_t)TOKS * 8 + (size_t)tok * 8 + k] = (float)(ex[k] / den);
        }
        const int bbb = tok >> 13;
#pragma unroll 1
        for (int k = 0; k < 8; ++k) {
          bool in_new = false, in_old = false;
          for (int j = 0; j < 8; ++j) {
            if (wi[j] == olde[k]) in_new = true;
            if (olde[j] == wi[k]) in_old = true;
          }
          if (!in_new) atomicAdd(&gce[bbb * 64 + olde[k]], -1.0f);
          if (!in_old) atomicAdd(&gce[bbb * 64 + wi[k]], 1.0f);
        }
      }
    }
  }
}

// ---------------- aux loss reduction ----------------
__global__ void moe_gate_aux(const float* __restrict__ gsum,
                             const float* __restrict__ gce,
                             float* __restrict__ out)
{
  __shared__ float r[256];
  const int tid = threadIdx.x;
  r[tid] = gce[tid] * gsum[tid];
  __syncthreads();
  for (int s = 128; s > 0; s >>= 1) {
    if (tid < s) r[tid] += r[tid + s];
    __syncthreads();
  }
  if (tid == 0)
    out[(size_t)TOKS * 16] = 0.1f * r[0] / ((float)SEQ * (float)NBATCH);
}

extern "C" void kernel_launch(void* const* d_in, const int* in_sizes, int n_in,
                              void* d_out, int out_size, void* d_ws, size_t ws_size,
                              hipStream_t stream)
{
  const float* X = (const float*)d_in[0];   // [4,8192,1024] fp32
  const float* W = (const float*)d_in[1];   // [64,1024] fp32
  float* out  = (float*)d_out;              // idx[T*8] | weights[T*8] | aux
  float* gsum = (float*)d_ws;               // [4][64]
  float* gce  = gsum + NBATCH * NEXP;       // [4][64]
  int* flag_cnt = (int*)((char*)d_ws + 2048);
  int* flag_tok = (int*)((char*)d_ws + 2176);
  // W3: fragment-ordered bf16 hi/lo (256 KiB) at +1 MiB
  ushort* W3 = (ushort*)((char*)d_ws + (1 << 20));

  hipMemsetAsync(d_ws, 0, 2176, stream);
  moe_wsplit<<<64, 256, 0, stream>>>(W, W3);
  moe_gate_main<<<TOKS / TPB, 256, 0, stream>>>(X, W3, out, gsum, gce, flag_cnt, flag_tok);
  moe_refine<<<256, 256, 0, stream>>>(X, W, out, gce, flag_cnt, flag_tok);
  moe_gate_aux<<<1, 256, 0, stream>>>(gsum, gce, out);
}

// Round 6
// 253.835 us; speedup vs baseline: 1.0044x; 1.0044x over previous
//
#include <hip/hip_runtime.h>

#define TOKS   32768
#define NEXP   64
#define DDIM   1024
#define SEQ    8192
#define NBATCH 4
#define TPB    64      // tokens per epilogue block
#define STR    68      // epilogue row stride (floats)
#define CSTR   21      // candidate row stride

typedef __attribute__((ext_vector_type(8)))  short short8v;  // 8 bf16 (4 VGPR) MFMA operand
typedef __attribute__((ext_vector_type(4)))  float f32x4;    // 16x16 accumulator

// exact RNE float->bf16 (branchless), and exact bf16->float
__device__ __forceinline__ unsigned f2bf(float x) {
  unsigned u = __float_as_uint(x);
  return (u + 0x7fffu + ((u >> 16) & 1u)) >> 16;
}
__device__ __forceinline__ float bf2f(unsigned h) { return __uint_as_float(h << 16); }

// ---------------- W split setup: fp32 W -> fragment-ordered bf16 hi/lo (W4) ----------------
// hi table @0, lo table @131072 B. Within a table: byte = g*4096 + e*64 + kh*16
// (g = K32-group 0..31, e = expert 0..63, kh = k8-quarter 0..3).
// A wave's B-frag load (16 experts x one kh per lane) is a dense 1KB region -> L2-resident.
__global__ void moe_wsplit(const float* __restrict__ W, ushort* __restrict__ W4) {
  const int sid = blockIdx.x * 256 + threadIdx.x;   // 0..16383 16B-slots
  const int table = sid >> 13;                      // 0 = hi, 1 = lo
  const int s2 = sid & 8191;
  const int g  = s2 >> 8;
  const int r  = s2 & 255;
  const int e  = r >> 2;
  const int kh = r & 3;
  const int k0 = g * 32 + kh * 8;
  const float* src = W + (size_t)e * DDIM + k0;
  float f[8];
  *(float4*)&f[0] = *(const float4*)src;
  *(float4*)&f[4] = *(const float4*)(src + 4);
  ushort o[8];
  if (table == 0) {
#pragma unroll
    for (int j = 0; j < 8; ++j) o[j] = (ushort)f2bf(f[j]);
  } else {
#pragma unroll
    for (int j = 0; j < 8; ++j) {
      unsigned hb = f2bf(f[j]);
      o[j] = (ushort)f2bf(f[j] - bf2f(hb));
    }
  }
  *(short8v*)(W4 + (size_t)sid * 8) = *(const short8v*)o;
}

// ---------------- GEMM: 16 tokens/block, 2048 blocks, 6 blocks/CU ----------------
// Each block reads a contiguous 64 KB X-slab. A from 16KB swizzled LDS (hi/lo dbuf),
// B direct from L2-resident W4. One barrier per 128-k chunk. Logits -> global.
__global__ __launch_bounds__(256, 6) void moe_gemm(
    const float* __restrict__ X, const ushort* __restrict__ W4,
    float* __restrict__ Lg)
{
  // buf0: Xh @0 (4K), Xl @4096; buf1: Xh @8192, Xl @12288
  __shared__ __align__(16) char smem[16384];

  const int tid = threadIdx.x;
  const int l = tid & 63, w = tid >> 6;
  const int tok_base = blockIdx.x * 16;

  // staging map: thread -> (row sr, 16B-slot sp); swizzled store slot = sp ^ sr
  const int sr = tid >> 4;
  const int sp = tid & 15;
  const float* Xr = X + (size_t)(tok_base + sr) * DDIM + sp * 8;
  const int wofs = sr * 256 + ((sp ^ sr) << 4);

  // compute map (m89/m91-verified 16x16x32): A row = l&15, k8-group kg = l>>4
  const int kg = l >> 4;
  const int abase = (l & 15) * 256;
  const int axor = l & 15;
  const char* Wb = (const char*)W4 + w * 1024 + (l & 15) * 64 + kg * 16;

  f32x4 acc = (f32x4)0.0f;
  float4 px0, px1;
  unsigned vh[4], vl[4];

#define LOADPX(kc) do { \
    px0 = *(const float4*)(Xr + (kc) * 128); \
    px1 = *(const float4*)(Xr + (kc) * 128 + 4); } while (0)

#define CONV() do { \
    float ff[8] = {px0.x, px0.y, px0.z, px0.w, px1.x, px1.y, px1.z, px1.w}; \
    _Pragma("unroll") \
    for (int i = 0; i < 4; ++i) { \
      unsigned h0 = f2bf(ff[2 * i]), h1 = f2bf(ff[2 * i + 1]); \
      vh[i] = h0 | (h1 << 16); \
      vl[i] = f2bf(ff[2 * i] - bf2f(h0)) | (f2bf(ff[2 * i + 1] - bf2f(h1)) << 16); \
    } } while (0)

#define WRITE(b) do { \
    *(uint4*)(smem + (b) * 8192 + wofs)        = make_uint4(vh[0], vh[1], vh[2], vh[3]); \
    *(uint4*)(smem + (b) * 8192 + 4096 + wofs) = make_uint4(vl[0], vl[1], vl[2], vl[3]); \
    } while (0)

#define COMPUTE(kc) do { \
    const char* base = smem + ((kc) & 1) * 8192; \
    _Pragma("unroll") \
    for (int s = 0; s < 4; ++s) { \
      const char* wp = Wb + (size_t)((kc) * 4 + s) * 4096; \
      short8v bh = *(const short8v*)wp; \
      short8v bl = *(const short8v*)(wp + 131072); \
      const int aoff = abase + (((4 * s + kg) ^ axor) << 4); \
      short8v ah = *(const short8v*)(base + aoff); \
      short8v al = *(const short8v*)(base + aoff + 4096); \
      acc = __builtin_amdgcn_mfma_f32_16x16x32_bf16(ah, bh, acc, 0, 0, 0); \
      acc = __builtin_amdgcn_mfma_f32_16x16x32_bf16(al, bh, acc, 0, 0, 0); \
      acc = __builtin_amdgcn_mfma_f32_16x16x32_bf16(ah, bl, acc, 0, 0, 0); \
    } } while (0)

  // prologue: fill buf0 with chunk 0; chunk 1 loads in flight
  LOADPX(0);
  CONV();
  WRITE(0);
  LOADPX(1);
  __syncthreads();

#pragma unroll 1
  for (int kc = 0; kc < 8; ++kc) {
    if (kc + 1 < 8) {            // convert+write next chunk (px loaded an iter ago)
      CONV();
      WRITE((kc + 1) & 1);
    }
    if (kc + 2 < 8) LOADPX(kc + 2);   // issue early: full chunk of slack
    COMPUTE(kc);
    __syncthreads();             // readers of buf[kc&1] and writers of buf[(kc+1)&1] done
  }

#undef LOADPX
#undef CONV
#undef WRITE
#undef COMPUTE

  // C/D (m89-verified): col = lane&15 (expert), row = kg*4 + r (token)
  {
    float* dst = Lg + (size_t)(tok_base + kg * 4) * NEXP + w * 16 + (l & 15);
#pragma unroll
    for (int r = 0; r < 4; ++r) dst[(size_t)r * NEXP] = acc[r];
  }
}

// ---------------- epilogue: stage logits, then proven round-3 epilogue ----------------
__global__ __launch_bounds__(256, 3) void moe_gate_epi(
    const float* __restrict__ Lg,
    float* __restrict__ out, float* __restrict__ gsum, float* __restrict__ gce,
    int* __restrict__ flag_cnt, int* __restrict__ flag_tok)
{
  __shared__ __align__(16) char smem[47104];

  float* xs   = (float*)smem;            // scoresT [64][STR]
  float* wsm  = (float*)(smem + 17408);  // logits  [64][STR]
  float* red  = (float*)(smem + 34816);  // [256]
  float* gmx  = (float*)(smem + 35840);  // [64]
  float* cval = (float*)(smem + 36096);  // [64*CSTR]
  int*   cidx = (int*)  (smem + 41472);  // [64*CSTR]
  int*   hist = (int*)  (smem + 46848);  // [64]

  const int tid = threadIdx.x;
  const int tok_base = blockIdx.x * TPB;
  const int bb = blockIdx.x >> 7;        // 128 blocks per batch
  const int l = tid & 63, q = tid >> 6;

  // stage logits [64][64] -> wsm [64][STR]
  const float* Ls = Lg + (size_t)tok_base * NEXP;
#pragma unroll
  for (int i = 0; i < 4; ++i) {
    const int id = i * 256 + tid;        // float4 id over [64][16]
    float4 v = *(const float4*)(Ls + id * 4);
    *(float4*)&wsm[(id >> 4) * STR + (id & 15) * 4] = v;
  }
  if (tid < 64) hist[tid] = 0;
  __syncthreads();

  // ---- epilogue (round-3 layout, unchanged) ----
  float* logits  = wsm;   // [t][STR]
  float* scoresT = xs;    // [e][STR]
  const int t = l;

  float m = -__builtin_huge_valf();
#pragma unroll
  for (int e = 0; e < 16; ++e) m = fmaxf(m, logits[t * STR + q * 16 + e]);
  red[q * 64 + t] = m;
  __syncthreads();
  float gm = fmaxf(fmaxf(red[t], red[64 + t]), fmaxf(red[128 + t], red[192 + t]));
  if (q == 0) gmx[t] = gm;
  float z = 0.0f;
#pragma unroll
  for (int e = 0; e < 16; ++e) {
    float ev = expf(logits[t * STR + q * 16 + e] - gm);
    scoresT[(q * 16 + e) * STR + t] = ev;
    z += ev;
  }
  __syncthreads();
  red[q * 64 + t] = z;
  __syncthreads();
  float Z = red[t] + red[64 + t] + red[128 + t] + red[192 + t];
  float invZ = 1.0f / Z;
#pragma unroll
  for (int e = 0; e < 16; ++e) scoresT[(q * 16 + e) * STR + t] *= invZ;
  __syncthreads();

  // aux partials: sum scores over this block's tokens, per expert
  {
    const int e = l, g = q;
    float s = 0.0f;
#pragma unroll
    for (int tt = 0; tt < 16; ++tt) s += scoresT[e * STR + g * 16 + tt];
    red[g * 64 + e] = s;
  }
  __syncthreads();
  if (tid < 64) {
    float tot = red[tid] + red[64 + tid] + red[128 + tid] + red[192 + tid];
    atomicAdd(&gsum[bb * 64 + tid], tot);
  }

  // top-9 phase 1: per half (32 experts), strict > + ascending scan == jax tie-break
  if (tid < 128) {
    const int h = tid >> 6;
    const int eb = h * 32;
#pragma unroll 1
    for (int k = 0; k < 9; ++k) {
      float mv = -1.0f; int mi = eb;
#pragma unroll 4
      for (int e = 0; e < 32; ++e) {
        float v = scoresT[(eb + e) * STR + t];
        if (v > mv) { mv = v; mi = eb + e; }
      }
      cval[t * CSTR + h * 9 + k] = mv;
      cidx[t * CSTR + h * 9 + k] = mi;
      scoresT[mi * STR + t] = -1.0f;
    }
  }
  __syncthreads();

  // merge 18 -> top-9; flag near-ties for f64 refinement
  if (tid < 64) {
    float wv[9]; int wi[8];
#pragma unroll 1
    for (int k = 0; k < 9; ++k) {
      float mv = -1.0f; int mj = 0;
#pragma unroll 3
      for (int j = 0; j < 18; ++j) {
        float v = cval[t * CSTR + j];
        if (v > mv) { mv = v; mj = j; }
      }
      wv[k] = mv;
      if (k < 8) {
        wi[k] = cidx[t * CSTR + mj];
        atomicAdd(&hist[wi[k]], 1);
      }
      cval[t * CSTR + mj] = -1.0f;
    }
    bool flag = false;
#pragma unroll
    for (int k = 0; k < 8; ++k)
      if (wv[k + 1] >= wv[k] * (1.0f - 2.0e-5f)) flag = true;
    if (flag) {
      int p = atomicAdd(flag_cnt, 1);
      flag_tok[p] = tok_base + t;
    }
    // weights from f64 exp of logits (Z cancels in renorm; eps 1e-20 negligible)
    double ed[8]; double den = 0.0;
#pragma unroll
    for (int k = 0; k < 8; ++k) {
      ed[k] = exp((double)logits[t * STR + wi[k]] - (double)gmx[t]);
      den += ed[k];
    }
    const size_t tg = (size_t)(tok_base + t);
    *(float4*)(out + tg * 8) =
        make_float4((float)wi[0], (float)wi[1], (float)wi[2], (float)wi[3]);
    *(float4*)(out + tg * 8 + 4) =
        make_float4((float)wi[4], (float)wi[5], (float)wi[6], (float)wi[7]);
    *(float4*)(out + (size_t)TOKS * 8 + tg * 8) =
        make_float4((float)(ed[0] / den), (float)(ed[1] / den),
                    (float)(ed[2] / den), (float)(ed[3] / den));
    *(float4*)(out + (size_t)TOKS * 8 + tg * 8 + 4) =
        make_float4((float)(ed[4] / den), (float)(ed[5] / den),
                    (float)(ed[6] / den), (float)(ed[7] / den));
  }
  __syncthreads();
  if (tid < 64) atomicAdd(&gce[bb * 64 + tid], (float)hist[tid]);
}

// ---------------- f64 refinement for flagged (near-tie) tokens ----------------
__global__ __launch_bounds__(256) void moe_refine(
    const float* __restrict__ X, const float* __restrict__ W,
    float* __restrict__ out, float* __restrict__ gce,
    const int* __restrict__ flag_cnt, const int* __restrict__ flag_tok)
{
  __shared__ __align__(16) float xrow[DDIM];
  __shared__ double part[4][NEXP];
  const int tid = threadIdx.x;
  const int n = *flag_cnt;
  const int e = tid & 63;
  const int c = tid >> 6;          // K-chunk of 256
#pragma unroll 1
  for (int it = blockIdx.x; it < n; it += 256) {
    const int tok = flag_tok[it];
    __syncthreads();
    *(float4*)&xrow[tid * 4] = *(const float4*)&X[(size_t)tok * DDIM + tid * 4];
    __syncthreads();
    const float* wr = W + (size_t)e * DDIM + c * 256;
    const float* xr = xrow + c * 256;
    double s0 = 0.0, s1 = 0.0, s2 = 0.0, s3 = 0.0;
#pragma unroll 4
    for (int j = 0; j < 256; j += 4) {
      s0 += (double)xr[j]     * (double)wr[j];
      s1 += (double)xr[j + 1] * (double)wr[j + 1];
      s2 += (double)xr[j + 2] * (double)wr[j + 2];
      s3 += (double)xr[j + 3] * (double)wr[j + 3];
    }
    part[c][e] = (s0 + s1) + (s2 + s3);
    __syncthreads();
    if (tid < 64) {
      double cur = (part[0][e] + part[1][e]) + (part[2][e] + part[3][e]);
      int wi[8]; double wl[8];
#pragma unroll 1
      for (int k = 0; k < 8; ++k) {
        double mv = cur; int mi = e;
#pragma unroll
        for (int off = 1; off < 64; off <<= 1) {
          double ov = __shfl_xor(mv, off);
          int    oi = __shfl_xor(mi, off);
          if (ov > mv || (ov == mv && oi < mi)) { mv = ov; mi = oi; }
        }
        wi[k] = mi; wl[k] = mv;
        if (e == mi) cur = -1.0e300;   // knock out winner in its owner lane
      }
      if (e == 0) {
        int olde[8];
#pragma unroll
        for (int k = 0; k < 8; ++k) olde[k] = (int)out[(size_t)tok * 8 + k];
        double ex[8]; double den = 0.0;
#pragma unroll
        for (int k = 0; k < 8; ++k) { ex[k] = exp(wl[k] - wl[0]); den += ex[k]; }
#pragma unroll
        for (int k = 0; k < 8; ++k) {
          out[(size_t)tok * 8 + k] = (float)wi[k];
          out[(size_t)TOKS * 8 + (size_t)tok * 8 + k] = (float)(ex[k] / den);
        }
        const int bbb = tok >> 13;
#pragma unroll 1
        for (int k = 0; k < 8; ++k) {
          bool in_new = false, in_old = false;
          for (int j = 0; j < 8; ++j) {
            if (wi[j] == olde[k]) in_new = true;
            if (olde[j] == wi[k]) in_old = true;
          }
          if (!in_new) atomicAdd(&gce[bbb * 64 + olde[k]], -1.0f);
          if (!in_old) atomicAdd(&gce[bbb * 64 + wi[k]], 1.0f);
        }
      }
    }
  }
}

// ---------------- aux loss reduction ----------------
__global__ void moe_gate_aux(const float* __restrict__ gsum,
                             const float* __restrict__ gce,
                             float* __restrict__ out)
{
  __shared__ float r[256];
  const int tid = threadIdx.x;
  r[tid] = gce[tid] * gsum[tid];
  __syncthreads();
  for (int s = 128; s > 0; s >>= 1) {
    if (tid < s) r[tid] += r[tid + s];
    __syncthreads();
  }
  if (tid == 0)
    out[(size_t)TOKS * 16] = 0.1f * r[0] / ((float)SEQ * (float)NBATCH);
}

extern "C" void kernel_launch(void* const* d_in, const int* in_sizes, int n_in,
                              void* d_out, int out_size, void* d_ws, size_t ws_size,
                              hipStream_t stream)
{
  const float* X = (const float*)d_in[0];   // [4,8192,1024] fp32
  const float* W = (const float*)d_in[1];   // [64,1024] fp32
  float* out  = (float*)d_out;              // idx[T*8] | weights[T*8] | aux
  float* gsum = (float*)d_ws;               // [4][64]
  float* gce  = gsum + NBATCH * NEXP;       // [4][64]
  int* flag_cnt = (int*)((char*)d_ws + 2048);
  int* flag_tok = (int*)((char*)d_ws + 2176);
  ushort* W4 = (ushort*)((char*)d_ws + (1 << 20));      // 256 KiB fragment tables
  float*  Lg = (float*)((char*)d_ws + (2 << 20));       // 8 MiB logits [TOKS][NEXP]

  hipMemsetAsync(d_ws, 0, 2176, stream);
  moe_wsplit<<<64, 256, 0, stream>>>(W, W4);
  moe_gemm<<<TOKS / 16, 256, 0, stream>>>(X, W4, Lg);
  moe_gate_epi<<<TOKS / TPB, 256, 0, stream>>>(Lg, out, gsum, gce, flag_cnt, flag_tok);
  moe_refine<<<256, 256, 0, stream>>>(X, W, out, gce, flag_cnt, flag_tok);
  moe_gate_aux<<<1, 256, 0, stream>>>(gsum, gce, out);
}

// Round 8
// 227.463 us; speedup vs baseline: 1.1208x; 1.1159x over previous
//
#include <hip/hip_runtime.h>
#include <hip/hip_bf16.h>

#define TOKS   32768
#define NEXP   64
#define DDIM   1024
#define SEQ    8192
#define NBATCH 4
#define TPB    64      // tokens per block
#define STR    68      // epilogue row stride (floats)
#define CSTR   21      // candidate row stride
#define BK     128     // K-chunk per staging step
#define NCH    (DDIM / BK)   // 8
#define ASTR   136     // bf16 row stride of staged tiles (+8 pad -> dense-equivalent banks)

typedef __attribute__((ext_vector_type(8))) short short8v;  // 8 bf16 = 4 VGPRs (MFMA A/B frag)
typedef __attribute__((ext_vector_type(4))) float f32x4;    // 16x16x32 accumulator
typedef float f4v __attribute__((ext_vector_type(4)));

// Non-temporal 16B load: X is streamed once; nt bypasses L3 allocation so X
// misses don't evict the harness-poison's dirty lines (hidden writebacks).
__device__ __forceinline__ float4 ntload4(const float* p) {
  f4v v = __builtin_nontemporal_load((const f4v*)p);
  return make_float4(v[0], v[1], v[2], v[3]);
}

// Split one float4 into bf16 hi (RNE) and bf16 lo = RNE(x - hi).
// hi*hi + hi*lo + lo*hi in f32-accum MFMA reproduces fp32 logits to ~1e-6 abs.
__device__ __forceinline__ void stage4(ushort* dh, ushort* dl, float4 v) {
  __hip_bfloat162 h0 = __float22bfloat162_rn(make_float2(v.x, v.y));
  __hip_bfloat162 h1 = __float22bfloat162_rn(make_float2(v.z, v.w));
  float2 f0 = __bfloat1622float2(h0);
  float2 f1 = __bfloat1622float2(h1);
  __hip_bfloat162 l0 = __float22bfloat162_rn(make_float2(v.x - f0.x, v.y - f0.y));
  __hip_bfloat162 l1 = __float22bfloat162_rn(make_float2(v.z - f1.x, v.w - f1.y));
  *(__hip_bfloat162*)(dh)     = h0;
  *(__hip_bfloat162*)(dh + 2) = h1;
  *(__hip_bfloat162*)(dl)     = l0;
  *(__hip_bfloat162*)(dl + 2) = l1;
}

// ---------------- main kernel: bf16x2 MFMA GEMM + softmax + top-9 + flagging ----------------
__global__ __launch_bounds__(256, 2) void moe_gate_main(
    const float* __restrict__ X, const float* __restrict__ W,
    float* __restrict__ out, float* __restrict__ gsum, float* __restrict__ gce,
    int* __restrict__ flag_cnt, int* __restrict__ flag_tok)
{
  // 69632 B pool: GEMM phase = 4 bf16 tiles [64][ASTR]; epilogue aliases the
  // same memory with the proven round-3 layout (47104 B).
  __shared__ __align__(16) char smem[4 * 64 * ASTR * 2];

  ushort* Ah = (ushort*)smem;            // X-tile hi  [64][ASTR]
  ushort* Al = Ah + 64 * ASTR;           // X-tile lo
  ushort* Bh = Al + 64 * ASTR;           // W-tile hi
  ushort* Bl = Bh + 64 * ASTR;           // W-tile lo

  float* xs   = (float*)smem;            // scoresT [64][STR]
  float* wsm  = (float*)(smem + 17408);  // logits  [64][STR]
  float* red  = (float*)(smem + 34816);  // [256]
  float* gmx  = (float*)(smem + 35840);  // [64]
  float* cval = (float*)(smem + 36096);  // [64*CSTR]
  int*   cidx = (int*)  (smem + 41472);  // [64*CSTR]
  int*   hist = (int*)  (smem + 46848);  // [64]

  const int tid = threadIdx.x;
  const int tok_base = blockIdx.x * TPB;
  const int bb = blockIdx.x >> 7;        // 128 blocks per batch

  const int l = tid & 63;
  const int q = tid >> 6;

  // staging map: 32 float4 cols x 8 rows per pass, 8 passes -> 64 rows x 128 f32
  const int c4 = tid & 31;
  const int r0 = tid >> 5;

  // MFMA map: wave q owns 32x32 quadrant (wm: token half, wn: expert half)
  const int wm = q >> 1, wn = q & 1;
  const int fr = l & 15;                 // row within 16-tile
  const int fk = (l >> 4) * 8;           // contiguous-8 k offset within K=32

  f32x4 accA[2][2], accB[2][2];
#pragma unroll
  for (int i = 0; i < 2; ++i)
#pragma unroll
    for (int j = 0; j < 2; ++j) {
      accA[i][j] = (f32x4)0.0f;
      accB[i][j] = (f32x4)0.0f;
    }

  float4 px[8], pw[8];
#pragma unroll
  for (int i = 0; i < 8; ++i) {
    px[i] = ntload4(X + (size_t)(tok_base + r0 + 8 * i) * DDIM + 4 * c4);
    pw[i] = *(const float4*)(W + (size_t)(r0 + 8 * i) * DDIM + 4 * c4);
  }

#pragma unroll 1
  for (int kt = 0; kt < NCH; ++kt) {
    __syncthreads();                     // prev MFMA done reading LDS
#pragma unroll
    for (int i = 0; i < 8; ++i) {
      const int row = r0 + 8 * i;
      stage4(&Ah[row * ASTR + 4 * c4], &Al[row * ASTR + 4 * c4], px[i]);
      stage4(&Bh[row * ASTR + 4 * c4], &Bl[row * ASTR + 4 * c4], pw[i]);
    }
    __syncthreads();
    if (kt + 1 < NCH) {
      const int db = (kt + 1) * BK;
#pragma unroll
      for (int i = 0; i < 8; ++i) {
        px[i] = ntload4(X + (size_t)(tok_base + r0 + 8 * i) * DDIM + db + 4 * c4);
        pw[i] = *(const float4*)(W + (size_t)(r0 + 8 * i) * DDIM + db + 4 * c4);
      }
    }
#pragma unroll
    for (int s = 0; s < BK / 32; ++s) {
      const int ko = s * 32 + fk;
      short8v a_h[2], a_l[2], b_h[2], b_l[2];
#pragma unroll
      for (int i = 0; i < 2; ++i) {
        const ushort* pa = Ah + (size_t)(32 * wm + 16 * i + fr) * ASTR + ko;
        a_h[i] = *(const short8v*)pa;
        a_l[i] = *(const short8v*)(pa + 64 * ASTR);
        const ushort* pb = Bh + (size_t)(32 * wn + 16 * i + fr) * ASTR + ko;
        b_h[i] = *(const short8v*)pb;
        b_l[i] = *(const short8v*)(pb + 64 * ASTR);
      }
#pragma unroll
      for (int i = 0; i < 2; ++i)
#pragma unroll
        for (int j = 0; j < 2; ++j) {
          accA[i][j] = __builtin_amdgcn_mfma_f32_16x16x32_bf16(a_h[i], b_h[j], accA[i][j], 0, 0, 0);
          accB[i][j] = __builtin_amdgcn_mfma_f32_16x16x32_bf16(a_l[i], b_h[j], accB[i][j], 0, 0, 0);
          accA[i][j] = __builtin_amdgcn_mfma_f32_16x16x32_bf16(a_h[i], b_l[j], accA[i][j], 0, 0, 0);
        }
    }
  }

  __syncthreads();                       // all MFMA reads done; smem -> epilogue layout
  // C/D layout (m89-verified): col = lane&15, row = (lane>>4)*4 + reg
#pragma unroll
  for (int i = 0; i < 2; ++i)
#pragma unroll
    for (int j = 0; j < 2; ++j) {
      f32x4 c = accA[i][j] + accB[i][j];
      const int tok = 32 * wm + 16 * i + 4 * (l >> 4);
      const int e   = 32 * wn + 16 * j + fr;
#pragma unroll
      for (int r = 0; r < 4; ++r)
        wsm[(tok + r) * STR + e] = c[r];
    }
  if (tid < 64) hist[tid] = 0;
  __syncthreads();

  // ---- epilogue (round-3 layout, unchanged) ----
  float* logits  = wsm;   // [t][STR]
  float* scoresT = xs;    // [e][STR]
  const int t = l;

  float m = -__builtin_huge_valf();
#pragma unroll
  for (int e = 0; e < 16; ++e) m = fmaxf(m, logits[t * STR + q * 16 + e]);
  red[q * 64 + t] = m;
  __syncthreads();
  float gm = fmaxf(fmaxf(red[t], red[64 + t]), fmaxf(red[128 + t], red[192 + t]));
  if (q == 0) gmx[t] = gm;
  float z = 0.0f;
#pragma unroll
  for (int e = 0; e < 16; ++e) {
    float ev = expf(logits[t * STR + q * 16 + e] - gm);
    scoresT[(q * 16 + e) * STR + t] = ev;
    z += ev;
  }
  __syncthreads();
  red[q * 64 + t] = z;
  __syncthreads();
  float Z = red[t] + red[64 + t] + red[128 + t] + red[192 + t];
  float invZ = 1.0f / Z;
#pragma unroll
  for (int e = 0; e < 16; ++e) scoresT[(q * 16 + e) * STR + t] *= invZ;
  __syncthreads();

  // aux partials: sum scores over this block's tokens, per expert
  {
    const int e = l, g = q;
    float s = 0.0f;
#pragma unroll
    for (int tt = 0; tt < 16; ++tt) s += scoresT[e * STR + g * 16 + tt];
    red[g * 64 + e] = s;
  }
  __syncthreads();
  if (tid < 64) {
    float tot = red[tid] + red[64 + tid] + red[128 + tid] + red[192 + tid];
    atomicAdd(&gsum[bb * 64 + tid], tot);
  }

  // top-9 phase 1: per half (32 experts), strict > + ascending scan == jax tie-break
  if (tid < 128) {
    const int h = tid >> 6;
    const int eb = h * 32;
#pragma unroll 1
    for (int k = 0; k < 9; ++k) {
      float mv = -1.0f; int mi = eb;
#pragma unroll 4
      for (int e = 0; e < 32; ++e) {
        float v = scoresT[(eb + e) * STR + t];
        if (v > mv) { mv = v; mi = eb + e; }
      }
      cval[t * CSTR + h * 9 + k] = mv;
      cidx[t * CSTR + h * 9 + k] = mi;
      scoresT[mi * STR + t] = -1.0f;
    }
  }
  __syncthreads();

  // merge 18 -> top-9; flag near-ties for f64 refinement
  if (tid < 64) {
    float wv[9]; int wi[8];
#pragma unroll 1
    for (int k = 0; k < 9; ++k) {
      float mv = -1.0f; int mj = 0;
#pragma unroll 3
      for (int j = 0; j < 18; ++j) {
        float v = cval[t * CSTR + j];
        if (v > mv) { mv = v; mj = j; }
      }
      wv[k] = mv;
      if (k < 8) {
        wi[k] = cidx[t * CSTR + mj];
        atomicAdd(&hist[wi[k]], 1);
      }
      cval[t * CSTR + mj] = -1.0f;
    }
    bool flag = false;
#pragma unroll
    for (int k = 0; k < 8; ++k)
      if (wv[k + 1] >= wv[k] * (1.0f - 2.0e-5f)) flag = true;
    if (flag) {
      int p = atomicAdd(flag_cnt, 1);
      flag_tok[p] = tok_base + t;
    }
    // weights from f64 exp of logits (Z cancels in renorm; eps 1e-20 negligible)
    double ed[8]; double den = 0.0;
#pragma unroll
    for (int k = 0; k < 8; ++k) {
      ed[k] = exp((double)logits[t * STR + wi[k]] - (double)gmx[t]);
      den += ed[k];
    }
    const size_t tg = (size_t)(tok_base + t);
    *(float4*)(out + tg * 8) =
        make_float4((float)wi[0], (float)wi[1], (float)wi[2], (float)wi[3]);
    *(float4*)(out + tg * 8 + 4) =
        make_float4((float)wi[4], (float)wi[5], (float)wi[6], (float)wi[7]);
    *(float4*)(out + (size_t)TOKS * 8 + tg * 8) =
        make_float4((float)(ed[0] / den), (float)(ed[1] / den),
                    (float)(ed[2] / den), (float)(ed[3] / den));
    *(float4*)(out + (size_t)TOKS * 8 + tg * 8 + 4) =
        make_float4((float)(ed[4] / den), (float)(ed[5] / den),
                    (float)(ed[6] / den), (float)(ed[7] / den));
  }
  __syncthreads();
  if (tid < 64) atomicAdd(&gce[bb * 64 + tid], (float)hist[tid]);
}

// ---------------- f64 refinement for flagged (near-tie) tokens ----------------
__global__ __launch_bounds__(256) void moe_refine(
    const float* __restrict__ X, const float* __restrict__ W,
    float* __restrict__ out, float* __restrict__ gce,
    const int* __restrict__ flag_cnt, const int* __restrict__ flag_tok)
{
  __shared__ __align__(16) float xrow[DDIM];
  __shared__ double part[4][NEXP];
  const int tid = threadIdx.x;
  const int n = *flag_cnt;
  const int e = tid & 63;
  const int c = tid >> 6;          // K-chunk of 256
#pragma unroll 1
  for (int it = blockIdx.x; it < n; it += 256) {
    const int tok = flag_tok[it];
    __syncthreads();
    *(float4*)&xrow[tid * 4] = *(const float4*)&X[(size_t)tok * DDIM + tid * 4];
    __syncthreads();
    const float* wr = W + (size_t)e * DDIM + c * 256;
    const float* xr = xrow + c * 256;
    double s0 = 0.0, s1 = 0.0, s2 = 0.0, s3 = 0.0;
#pragma unroll 4
    for (int j = 0; j < 256; j += 4) {
      s0 += (double)xr[j]     * (double)wr[j];
      s1 += (double)xr[j + 1] * (double)wr[j + 1];
      s2 += (double)xr[j + 2] * (double)wr[j + 2];
      s3 += (double)xr[j + 3] * (double)wr[j + 3];
    }
    part[c][e] = (s0 + s1) + (s2 + s3);
    __syncthreads();
    if (tid < 64) {
      double cur = (part[0][e] + part[1][e]) + (part[2][e] + part[3][e]);
      int wi[8]; double wl[8];
#pragma unroll 1
      for (int k = 0; k < 8; ++k) {
        double mv = cur; int mi = e;
#pragma unroll
        for (int off = 1; off < 64; off <<= 1) {
          double ov = __shfl_xor(mv, off);
          int    oi = __shfl_xor(mi, off);
          if (ov > mv || (ov == mv && oi < mi)) { mv = ov; mi = oi; }
        }
        wi[k] = mi; wl[k] = mv;
        if (e == mi) cur = -1.0e300;   // knock out winner in its owner lane
      }
      if (e == 0) {
        int olde[8];
#pragma unroll
        for (int k = 0; k < 8; ++k) olde[k] = (int)out[(size_t)tok * 8 + k];
        double ex[8]; double den = 0.0;
#pragma unroll
        for (int k = 0; k < 8; ++k) { ex[k] = exp(wl[k] - wl[0]); den += ex[k]; }
#pragma unroll
        for (int k = 0; k < 8; ++k) {
          out[(size_t)tok * 8 + k] = (float)wi[k];
          out[(size_t)TOKS * 8 + (size_t)tok * 8 + k] = (float)(ex[k] / den);
        }
        const int bbb = tok >> 13;
#pragma unroll 1
        for (int k = 0; k < 8; ++k) {
          bool in_new = false, in_old = false;
          for (int j = 0; j < 8; ++j) {
            if (wi[j] == olde[k]) in_new = true;
            if (olde[j] == wi[k]) in_old = true;
          }
          if (!in_new) atomicAdd(&gce[bbb * 64 + olde[k]], -1.0f);
          if (!in_old) atomicAdd(&gce[bbb * 64 + wi[k]], 1.0f);
        }
      }
    }
  }
}

// ---------------- aux loss reduction ----------------
__global__ void moe_gate_aux(const float* __restrict__ gsum,
                             const float* __restrict__ gce,
                             float* __restrict__ out)
{
  __shared__ float r[256];
  const int tid = threadIdx.x;
  r[tid] = gce[tid] * gsum[tid];
  __syncthreads();
  for (int s = 128; s > 0; s >>= 1) {
    if (tid < s) r[tid] += r[tid + s];
    __syncthreads();
  }
  if (tid == 0)
    out[(size_t)TOKS * 16] = 0.1f * r[0] / ((float)SEQ * (float)NBATCH);
}

extern "C" void kernel_launch(void* const* d_in, const int* in_sizes, int n_in,
                              void* d_out, int out_size, void* d_ws, size_t ws_size,
                              hipStream_t stream)
{
  const float* X = (const float*)d_in[0];   // [4,8192,1024] fp32
  const float* W = (const float*)d_in[1];   // [64,1024] fp32
  float* out  = (float*)d_out;              // idx[T*8] | weights[T*8] | aux
  float* gsum = (float*)d_ws;               // [4][64]
  float* gce  = gsum + NBATCH * NEXP;       // [4][64]
  int* flag_cnt = (int*)((char*)d_ws + 2048);
  int* flag_tok = (int*)((char*)d_ws + 2176);

  hipMemsetAsync(d_ws, 0, 2176, stream);
  moe_gate_main<<<TOKS / TPB, 256, 0, stream>>>(X, W, out, gsum, gce, flag_cnt, flag_tok);
  moe_refine<<<256, 256, 0, stream>>>(X, W, out, gce, flag_cnt, flag_tok);
  moe_gate_aux<<<1, 256, 0, stream>>>(gsum, gce, out);
}